// Round 3
// baseline (346.418 us; speedup 1.0000x reference)
//
#include <hip/hip_runtime.h>

#define IN_F 128
#define OUT_F 32
#define XS_STRIDE 132   // 128 + 4 pad: keeps 16B alignment for b128, breaks bank aliasing

typedef float  vfloat4 __attribute__((ext_vector_type(4)));

// Pack two fp32 into one uint holding (bf16(a) low, bf16(b) high), RNE.
__device__ __forceinline__ unsigned int pack_bf16x2(float a, float b) {
    unsigned int ua = __float_as_uint(a);
    unsigned int ub = __float_as_uint(b);
    ua = (ua + 0x7FFFu + ((ua >> 16) & 1u)) >> 16;
    ub = (ub + 0x7FFFu + ((ub >> 16) & 1u)) & 0xFFFF0000u;
    return ua | ub;
}

// ---------------------------------------------------------------------------
// Kernel 1: z = bf16(x @ W + b)
// Block 256 = 4 waves. 64 rows/block. thread = (row = t&63, colgroup = t>>6).
// x tile staged in LDS (64 x 132 floats, 33.8 KB); read back as ds_read_b128
// with lane==row (conflict-benign). W/b accesses are wave-uniform -> scalar
// loads (s_load) on the SMEM pipe; inner loop is pure v_fmac. VALU-bound.
// ---------------------------------------------------------------------------
__global__ __launch_bounds__(256) void zgemm_kernel(
    const float* __restrict__ x, const float* __restrict__ W,
    const float* __restrict__ b, unsigned int* __restrict__ zb, int n_nodes)
{
    __shared__ float xs[64 * XS_STRIDE];

    const int t = threadIdx.x;
    const int row0 = blockIdx.x * 64;
    const int rows = min(64, n_nodes - row0);

    // Stage x tile: rows*32 float4, coalesced global read.
    {
        const float4* xv = (const float4*)(x + (size_t)row0 * IN_F);
        const int nv = rows * (IN_F / 4);
        for (int i = t; i < nv; i += 256) {
            const int r  = i >> 5;
            const int c4 = i & 31;
            *(float4*)&xs[r * XS_STRIDE + c4 * 4] = xv[i];
        }
    }
    __syncthreads();

    const int row = t & 63;        // lane id within wave == row
    const int cg  = t >> 6;        // 0..3, uniform per wave
    const float* __restrict__ Wc = W + cg * 8;

    float acc[8];
    #pragma unroll
    for (int c = 0; c < 8; ++c) acc[c] = 0.f;

    #pragma unroll 8
    for (int k4 = 0; k4 < IN_F / 4; ++k4) {
        const float4 xv = *(const float4*)&xs[row * XS_STRIDE + k4 * 4];
        const float xk[4] = {xv.x, xv.y, xv.z, xv.w};
        #pragma unroll
        for (int kk = 0; kk < 4; ++kk) {
            const int k = k4 * 4 + kk;
            #pragma unroll
            for (int c = 0; c < 8; ++c)
                acc[c] = fmaf(xk[kk], Wc[k * OUT_F + c], acc[c]);
        }
    }

    if (row < rows) {
        const float* __restrict__ bc = b + cg * 8;
        float v[8];
        #pragma unroll
        for (int c = 0; c < 8; ++c) v[c] = acc[c] + bc[c];
        uint4 o;
        o.x = pack_bf16x2(v[0], v[1]);
        o.y = pack_bf16x2(v[2], v[3]);
        o.z = pack_bf16x2(v[4], v[5]);
        o.w = pack_bf16x2(v[6], v[7]);
        // z row = 16 uints (32 bf16); this thread owns uints cg*4 .. cg*4+3
        *(uint4*)(zb + (size_t)(row0 + row) * 16 + cg * 4) = o;
    }
}

// ---------------------------------------------------------------------------
// Kernel 2: out[e][:] = vals[e] * (z[rows[e]][:] + z[cols[e]][:])
// 8 lanes/edge, 4 cols/lane. Gathers: 64 B contiguous segments from the
// 6.4 MB bf16 z (L2/L3 resident; plain loads). Stores: float4/lane, fully
// contiguous 1 KB per wave instruction, nontemporal to spare L2 for z.
// ---------------------------------------------------------------------------
__global__ __launch_bounds__(256) void edge_kernel(
    const int* __restrict__ erows, const int* __restrict__ ecols,
    const float* __restrict__ evals, const unsigned int* __restrict__ zb,
    float* __restrict__ out, int n_edges)
{
    const size_t g = (size_t)blockIdx.x * 256 + threadIdx.x;
    const size_t e = g >> 3;
    if (e >= (size_t)n_edges) return;
    const int l8 = (int)(g & 7);           // 0..7 -> cols l8*4 .. l8*4+3

    const int   r = __builtin_nontemporal_load(erows + e);
    const int   c = __builtin_nontemporal_load(ecols + e);
    const float w = __builtin_nontemporal_load(evals + e);

    // 2 bf16 pairs = 4 cols per lane
    const uint2 ur = *(const uint2*)(zb + (size_t)r * 16 + l8 * 2);
    const uint2 uc = *(const uint2*)(zb + (size_t)c * 16 + l8 * 2);

    vfloat4 o;
    o.x = w * (__uint_as_float(ur.x << 16)         + __uint_as_float(uc.x << 16));
    o.y = w * (__uint_as_float(ur.x & 0xFFFF0000u) + __uint_as_float(uc.x & 0xFFFF0000u));
    o.z = w * (__uint_as_float(ur.y << 16)         + __uint_as_float(uc.y << 16));
    o.w = w * (__uint_as_float(ur.y & 0xFFFF0000u) + __uint_as_float(uc.y & 0xFFFF0000u));

    vfloat4* dst = (vfloat4*)(out + e * OUT_F + l8 * 4);
    __builtin_nontemporal_store(o, dst);
}

extern "C" void kernel_launch(void* const* d_in, const int* in_sizes, int n_in,
                              void* d_out, int out_size, void* d_ws, size_t ws_size,
                              hipStream_t stream)
{
    const float* x  = (const float*)d_in[0];   // (100000, 128)
    const float* W  = (const float*)d_in[1];   // (128, 32)
    const float* b  = (const float*)d_in[2];   // (32,)
    const int* erow = (const int*)d_in[3];     // (E,) int32
    const int* ecol = (const int*)d_in[4];     // (E,) int32
    const float* ev = (const float*)d_in[5];   // (E,)

    const int n_nodes = in_sizes[0] / IN_F;
    const int n_edges = in_sizes[3];

    unsigned int* zb = (unsigned int*)d_ws;    // n_nodes * 16 uints = 6.4 MB
    float* out = (float*)d_out;                // (E, 32) fp32

    const int gemm_blocks = (n_nodes + 63) / 64;
    zgemm_kernel<<<gemm_blocks, 256, 0, stream>>>(x, W, b, zb, n_nodes);

    const size_t total_thr = (size_t)n_edges * 8;
    const int edge_blocks = (int)((total_thr + 255) / 256);
    edge_kernel<<<edge_blocks, 256, 0, stream>>>(erow, ecol, ev, zb, out, n_edges);
}